// Round 11
// baseline (127.595 us; speedup 1.0000x reference)
//
#include <hip/hip_runtime.h>

#define NAG 16
#define SPB 4        // scenes per block, one M=64 batch, single pass
#define NBLK 2048
#define TPB 512      // 8 waves
#define R2f 64.0f

typedef unsigned short u16;
typedef __attribute__((ext_vector_type(8))) short short8;
typedef __attribute__((ext_vector_type(4))) float f32x4;

#define MFMA(a, b, c) __builtin_amdgcn_mfma_f32_16x16x32_bf16(a, b, c, 0, 0, 0)

// ws blob offsets in u16 units (R3-proven layout)
#define OFF_B1 0        // [Wroot1;Wrel1]  K=128 N=128  S=4 T=8  (root s0..1, rel s2..3)
#define OFF_B2 16384    // [Wroot2;Wrel2]  K=256 N=128  S=8 T=8  (root s0..3, rel s4..7)
#define OFF_H1 49152    // Wh1             K=256 N=64   S=8 T=4
#define OFF_H2 65536    // Wh2             K=64  N=32   S=2 T=2
#define OFF_H3 67584    // Wh3             K=32  N=16   S=1 T=1
#define SWZ_UNITS 8512

__device__ __forceinline__ u16 f2b(float f) {            // RNE (swizzle only)
    unsigned u = __float_as_uint(f);
    unsigned r = u + 0x7FFFu + ((u >> 16) & 1u);
    return (u16)(r >> 16);
}
__device__ __forceinline__ unsigned pk2(float a, float b) {   // fast rnd, ties-up
    return ((__float_as_uint(a) + 0x8000u) >> 16) |
           ((__float_as_uint(b) + 0x8000u) & 0xFFFF0000u);
}

// ---------------- weight pre-swizzle: W[K][N] f32 -> fragment order bf16 -----
__global__ __launch_bounds__(256) void swizzle_w(
    const float* __restrict__ Wrel1, const float* __restrict__ Wroot1,
    const float* __restrict__ Wrel2, const float* __restrict__ Wroot2,
    const float* __restrict__ Wh1,  const float* __restrict__ Wh2,
    const float* __restrict__ Wh3,  u16* __restrict__ ws)
{
    const int u = blockIdx.x * 256 + threadIdx.x;
    if (u >= SWZ_UNITS) return;
    int v, T, N, ksplit;
    const float *W, *W2;
    u16* dst;
    if (u < 2048)      { v = u;        T = 8; N = 128; ksplit = 64;  W = Wroot1; W2 = Wrel1; dst = ws + OFF_B1 + v * 8; }
    else if (u < 6144) { v = u - 2048; T = 8; N = 128; ksplit = 128; W = Wroot2; W2 = Wrel2; dst = ws + OFF_B2 + v * 8; }
    else if (u < 8192) { v = u - 6144; T = 4; N = 64;  ksplit = 1 << 30; W = Wh1; W2 = Wh1; dst = ws + OFF_H1 + v * 8; }
    else if (u < 8448) { v = u - 8192; T = 2; N = 32;  ksplit = 1 << 30; W = Wh2; W2 = Wh2; dst = ws + OFF_H2 + v * 8; }
    else               { v = u - 8448; T = 1; N = 16;  ksplit = 1 << 30; W = Wh3; W2 = Wh3; dst = ws + OFF_H3 + v * 8; }
    const int lane = v & 63;
    const int t = (v >> 6) % T;
    const int s = (v >> 6) / T;
    const int n = t * 16 + (lane & 15);
    const int k0 = s * 32 + (lane >> 4) * 8;
    #pragma unroll
    for (int j = 0; j < 8; ++j) {
        const int k = k0 + j;
        const float val = (k < ksplit) ? W[k * N + n] : W2[(k - ksplit) * N + n];
        dst[j] = f2b(val);
    }
}

// blob fragment: serves as B-frag of W (k,n) AND A-frag of W^T (m,k) — identical bytes
__device__ __forceinline__ short8 ldfrag(const u16* __restrict__ ws, int off,
                                         int T, int s, int tile, int lane) {
    return *(const short8*)(ws + off + (size_t)(((s * T + tile) * 64 + lane) * 8));
}

// adjacency fragment for scene g inside a 32-row pair window (2 scenes/window):
// element (lane, j) -> (row k = q*8+j, agent ln); zero outside g's 16-row half.
// Works as B-frag (k,n=ln) for D^T += y^T@adj (adj symmetric).
__device__ __forceinline__ short8 make_adj(unsigned m, int q, int odd) {
    union { short8 v; unsigned u[4]; } r;
    const bool on = (q >> 1) == odd;
    const int base = (q & 1) * 8;
    #pragma unroll
    for (int jj = 0; jj < 4; ++jj) {
        const int k0 = base + 2 * jj;
        const unsigned lo = (on && ((m >> k0) & 1u)) ? 0x3F80u : 0u;
        const unsigned hi = (on && ((m >> (k0 + 1)) & 1u)) ? 0x3F80u : 0u;
        r.u[jj] = lo | (hi << 16);
    }
    return r.v;
}

__device__ __forceinline__ void relu_store4(u16* d, f32x4 a) {
    uint2 u;
    u.x = pk2(fmaxf(a[0], 0.f), fmaxf(a[1], 0.f));
    u.y = pk2(fmaxf(a[2], 0.f), fmaxf(a[3], 0.f));
    *(uint2*)d = u;
}

// LDS (u16): xb [64][136] row-major (x; later x2)       0..8704
//            yT [128][72] ch-major (y; later h1[64][72] row-major)  8704..17920
//            x1b [64][136] row-major (x1; later h2[64][40])         17920..26624
// Hybrid orientation: y-GEMM normal (C -> b64 into ch-major yT);
// main GEMMs transposed (A=W^T from ws, B=act row-major b128,
// C -> b64 into row-major next-act). Zero scalar LDS stores.
__global__ __launch_bounds__(TPB) void gnn_fused7(
    const float* __restrict__ x, const float* __restrict__ pos,
    const float* __restrict__ brel1, const float* __restrict__ brel2,
    const float* __restrict__ bh1,  const float* __restrict__ bh2,
    const float* __restrict__ bh3,
    const u16* __restrict__ ws, float* __restrict__ out)
{
    __shared__ __align__(16) u16 pool[26624];
    __shared__ unsigned mask[64];
    u16* const xb  = pool;          // x, then x2
    u16* const yT  = pool + 8704;   // y (ch-major), then h1 (row-major [64][72])
    u16* const x1b = pool + 17920;  // x1, then h2 ([64][40])

    const int t = threadIdx.x;
    const int wv = t >> 6, lane = t & 63, ln = lane & 15, q = lane >> 4;
    const int c0 = 16 * wv;                 // wave's out-ch tile (L1/L2)
    const size_t sA = (size_t)blockIdx.x * SPB;

    // ---- S0: stage x (f32->bf16, row-major) + adjacency masks ----
    {
        const int r = t >> 3, co = (t & 7) * 8;
        const float* src = x + (sA * 16 + r) * 64 + co;
        const float4 v0 = *(const float4*)(src);
        const float4 v1 = *(const float4*)(src + 4);
        uint4 ua;
        ua.x = pk2(v0.x, v0.y); ua.y = pk2(v0.z, v0.w);
        ua.z = pk2(v1.x, v1.y); ua.w = pk2(v1.z, v1.w);
        *(uint4*)&xb[r * 136 + co] = ua;
    }
    if (t < 64) {
        const int g = t >> 4, a = t & 15;
        const float* pp = pos + (sA + g) * (NAG * 2);
        const float ax = pp[2 * a], ay = pp[2 * a + 1];
        unsigned m = 0;
        for (int j = 0; j < NAG; ++j) {
            const float dx = ax - pp[2 * j], dy = ay - pp[2 * j + 1];
            if (dx * dx + dy * dy <= R2f && j != a) m |= (1u << j);
        }
        mask[g * 16 + a] = m;
    }
    __syncthreads();

    short8 adjB[4];
    #pragma unroll
    for (int g = 0; g < 4; ++g) adjB[g] = make_adj(mask[g * 16 + ln], q, g & 1);

    // ---- L1: x1^T = Wroot1^T@x^T + y^T@adj + b ; y = x@Wrel1 (normal) ----
    {
        short8 Wrl[2], Wro[2];
        #pragma unroll
        for (int s = 0; s < 2; ++s) {
            Wrl[s] = ldfrag(ws, OFF_B1, 8, s + 2, wv, lane);
            Wro[s] = ldfrag(ws, OFF_B1, 8, s, wv, lane);
        }
        const float4 bv = *(const float4*)(brel1 + c0 + q * 4);
        #pragma unroll
        for (int p = 0; p < 2; ++p) {           // scene pair p: rows 32p..32p+31
            short8 Bx[2][2];
            #pragma unroll
            for (int gi = 0; gi < 2; ++gi) {    // y-pass (normal: A=x, B=Wrel)
                const int g = 2 * p + gi;
                Bx[gi][0] = *(const short8*)&xb[(g * 16 + ln) * 136 + q * 8];
                Bx[gi][1] = *(const short8*)&xb[(g * 16 + ln) * 136 + 32 + q * 8];
                f32x4 ay = {0.f, 0.f, 0.f, 0.f};
                ay = MFMA(Bx[gi][0], Wrl[0], ay);
                ay = MFMA(Bx[gi][1], Wrl[1], ay);
                uint2 u; u.x = pk2(ay[0], ay[1]); u.y = pk2(ay[2], ay[3]);
                *(uint2*)&yT[(c0 + ln) * 72 + g * 16 + q * 4] = u;   // ch-major b64
            }
            const short8 yA = *(const short8*)&yT[(c0 + ln) * 72 + p * 32 + q * 8];
            #pragma unroll
            for (int gi = 0; gi < 2; ++gi) {    // main (transposed: A=W^T/y^T, B=x/adj)
                const int g = 2 * p + gi;
                f32x4 a = {bv.x, bv.y, bv.z, bv.w};
                a = MFMA(Wro[0], Bx[gi][0], a);
                a = MFMA(Wro[1], Bx[gi][1], a);
                a = MFMA(yA, adjB[g], a);
                relu_store4(&x1b[(g * 16 + ln) * 136 + c0 + q * 4], a);  // row-major b64
            }
        }
    }
    __syncthreads();

    // ---- L2: x2^T = Wroot2^T@x1^T + y2^T@adj + b ; y2 = x1@Wrel2 ----
    {
        short8 Wrl[4], Wro[4];
        #pragma unroll
        for (int s = 0; s < 4; ++s) {
            Wrl[s] = ldfrag(ws, OFF_B2, 8, s + 4, wv, lane);
            Wro[s] = ldfrag(ws, OFF_B2, 8, s, wv, lane);
        }
        const float4 bv = *(const float4*)(brel2 + c0 + q * 4);
        #pragma unroll
        for (int p = 0; p < 2; ++p) {
            short8 Bx[2][4];
            #pragma unroll
            for (int gi = 0; gi < 2; ++gi) {
                const int g = 2 * p + gi;
                f32x4 ay = {0.f, 0.f, 0.f, 0.f};
                #pragma unroll
                for (int s = 0; s < 4; ++s) {
                    Bx[gi][s] = *(const short8*)&x1b[(g * 16 + ln) * 136 + s * 32 + q * 8];
                    ay = MFMA(Bx[gi][s], Wrl[s], ay);
                }
                uint2 u; u.x = pk2(ay[0], ay[1]); u.y = pk2(ay[2], ay[3]);
                *(uint2*)&yT[(c0 + ln) * 72 + g * 16 + q * 4] = u;
            }
            const short8 yA = *(const short8*)&yT[(c0 + ln) * 72 + p * 32 + q * 8];
            #pragma unroll
            for (int gi = 0; gi < 2; ++gi) {
                const int g = 2 * p + gi;
                f32x4 a = {bv.x, bv.y, bv.z, bv.w};
                #pragma unroll
                for (int s = 0; s < 4; ++s) a = MFMA(Wro[s], Bx[gi][s], a);
                a = MFMA(yA, adjB[g], a);
                relu_store4(&xb[(g * 16 + ln) * 136 + c0 + q * 4], a);   // x2 (x dead)
            }
        }
    }
    __syncthreads();

    // ---- G3: h1^T = Wh1^T @ [x1|x2]^T + bh1 ; wave = (ch-tile, row-half) ----
    {
        const int mt = wv & 3, h = wv >> 2;
        short8 Wf[8];
        #pragma unroll
        for (int s = 0; s < 8; ++s) Wf[s] = ldfrag(ws, OFF_H1, 4, s, mt, lane);
        const float4 bv = *(const float4*)(bh1 + mt * 16 + q * 4);
        u16* const h1 = yT;                      // y dead -> h1 row-major [64][72]
        #pragma unroll
        for (int ni = 0; ni < 2; ++ni) {
            const int nt = 2 * h + ni;
            f32x4 a = {bv.x, bv.y, bv.z, bv.w};
            #pragma unroll
            for (int s = 0; s < 4; ++s) {
                const short8 B1 = *(const short8*)&x1b[(nt * 16 + ln) * 136 + s * 32 + q * 8];
                const short8 B2 = *(const short8*)&xb[(nt * 16 + ln) * 136 + s * 32 + q * 8];
                a = MFMA(Wf[s], B1, a);
                a = MFMA(Wf[s + 4], B2, a);
            }
            relu_store4(&h1[(nt * 16 + ln) * 72 + mt * 16 + q * 4], a);
        }
    }
    __syncthreads();

    // ---- G4+G5 (wave-local: waves 0..3 = scenes): h2 then out ----
    if (wv < 4) {
        const int sc = wv;
        const u16* const h1 = yT;
        u16* const h2 = x1b;                     // x1 dead -> h2 [64][40]
        const short8 Bh0 = *(const short8*)&h1[(sc * 16 + ln) * 72 + q * 8];
        const short8 Bh1f = *(const short8*)&h1[(sc * 16 + ln) * 72 + 32 + q * 8];
        #pragma unroll
        for (int mt = 0; mt < 2; ++mt) {
            const short8 W0 = ldfrag(ws, OFF_H2, 2, 0, mt, lane);
            const short8 W1 = ldfrag(ws, OFF_H2, 2, 1, mt, lane);
            const float4 bv = *(const float4*)(bh2 + mt * 16 + q * 4);
            f32x4 a = {bv.x, bv.y, bv.z, bv.w};
            a = MFMA(W0, Bh0, a);
            a = MFMA(W1, Bh1f, a);
            relu_store4(&h2[(sc * 16 + ln) * 40 + mt * 16 + q * 4], a);
        }
        const short8 Bh2 = *(const short8*)&h2[(sc * 16 + ln) * 40 + q * 8];
        const short8 W3 = ldfrag(ws, OFF_H3, 1, 0, 0, lane);
        const float4 bv = *(const float4*)(bh3 + q * 4);
        f32x4 a = {bv.x, bv.y, bv.z, bv.w};
        a = MFMA(W3, Bh2, a);
        // D^T: m = out-ch q*4+r (consecutive), n = agent ln -> coalesced f32x4
        float4 o; o.x = a[0]; o.y = a[1]; o.z = a[2]; o.w = a[3];
        *(float4*)(out + ((sA + sc) * 16 + ln) * 16 + q * 4) = o;
    }
}

extern "C" void kernel_launch(void* const* d_in, const int* in_sizes, int n_in,
                              void* d_out, int out_size, void* d_ws, size_t ws_size,
                              hipStream_t stream) {
    const float* x      = (const float*)d_in[0];
    const float* pos    = (const float*)d_in[1];
    const float* Wrel1  = (const float*)d_in[2];
    const float* brel1  = (const float*)d_in[3];
    const float* Wroot1 = (const float*)d_in[4];
    const float* Wrel2  = (const float*)d_in[5];
    const float* brel2  = (const float*)d_in[6];
    const float* Wroot2 = (const float*)d_in[7];
    const float* Wh1    = (const float*)d_in[8];
    const float* bh1    = (const float*)d_in[9];
    const float* Wh2    = (const float*)d_in[10];
    const float* bh2    = (const float*)d_in[11];
    const float* Wh3    = (const float*)d_in[12];
    const float* bh3    = (const float*)d_in[13];
    u16* ws = (u16*)d_ws;

    swizzle_w<<<(SWZ_UNITS + 255) / 256, 256, 0, stream>>>(
        Wrel1, Wroot1, Wrel2, Wroot2, Wh1, Wh2, Wh3, ws);
    gnn_fused7<<<NBLK, TPB, 0, stream>>>(
        x, pos, brel1, brel2, bh1, bh2, bh3, ws, (float*)d_out);
}